// Round 6
// baseline (379.447 us; speedup 1.0000x reference)
//
#include <hip/hip_runtime.h>
#include <stdint.h>

#define NSIMS 2048
#define NDIM 8
#define NE (NSIMS * NDIM)      // 16384 elements per timestep
#define NSTEPS 1500
#define TP1 (NSTEPS + 1)       // 1501 trajectory columns

// ws layout (bytes)
#define KEYS_OFF 0u            // 1500 * uint2
#define WL_OFF 16384u          // 256 * int   (per-wave last valid tau)
#define PSTATE_OFF 32768u      // 16384 * float (pre state at freeze/chunk end)
#define BUF0_OFF 131072u       // Tc rows * 16384 floats (noise -> pre, in place)

// ---------------- Threefry2x32-20 (exact JAX/Random123) ----------------
__device__ __forceinline__ void tf_block(uint32_t k0, uint32_t k1,
                                         uint32_t x0, uint32_t x1,
                                         uint32_t& o0, uint32_t& o1) {
  const uint32_t k2 = k0 ^ k1 ^ 0x1BD11BDAu;
  x0 += k0; x1 += k1;
#define TF_R(r) { x0 += x1; x1 = (x1 << (r)) | (x1 >> (32 - (r))); x1 ^= x0; }
  TF_R(13) TF_R(15) TF_R(26) TF_R(6)
  x0 += k1; x1 += k2 + 1u;
  TF_R(17) TF_R(29) TF_R(16) TF_R(24)
  x0 += k2; x1 += k0 + 2u;
  TF_R(13) TF_R(15) TF_R(26) TF_R(6)
  x0 += k0; x1 += k1 + 3u;
  TF_R(17) TF_R(29) TF_R(16) TF_R(24)
  x0 += k1; x1 += k2 + 4u;
  TF_R(13) TF_R(15) TF_R(26) TF_R(6)
  x0 += k2; x1 += k0 + 5u;
#undef TF_R
  o0 = x0; o1 = x1;
}

// bits -> uniform(-0.99999994, 1) -> sqrt(2)*erfinv  (XLA constants/order)
__device__ __forceinline__ float bits_to_normal(uint32_t bits) {
#pragma clang fp contract(off)
  const float LO = -0.99999994f;  // nextafter(-1, 0); (hi - lo) == 2.0f in f32
  float f = __uint_as_float((bits >> 9) | 0x3F800000u) - 1.0f;  // [0,1)
  float u = f * 2.0f + LO;
  u = fmaxf(LO, u);
  float x2 = u * u;
  float w = -log1pf(-x2);
  float p;
  if (w < 5.0f) {
    w = w - 2.5f;
    p = 2.81022636e-08f;
    p = 3.43273939e-07f + p * w;
    p = -3.5233877e-06f + p * w;
    p = -4.39150654e-06f + p * w;
    p = 0.00021858087f + p * w;
    p = -0.00125372503f + p * w;
    p = -0.00417768164f + p * w;
    p = 0.246640727f + p * w;
    p = 1.50140941f + p * w;
  } else {
    w = sqrtf(w) - 3.0f;
    p = -0.000200214257f;
    p = 0.000100950558f + p * w;
    p = 0.00134934322f + p * w;
    p = -0.00367342844f + p * w;
    p = 0.00573950773f + p * w;
    p = -0.0076224613f + p * w;
    p = 0.00943887047f + p * w;
    p = 1.00167406f + p * w;
    p = 2.83297682f + p * w;
  }
  float ei = p * u;
  return 1.41421356f * ei;   // float32(sqrt(2)) = 0x3FB504F3
}

// ---------------- kernel 0: fold keys for all t ----------------
__global__ void k_fold(uint2* __restrict__ keys) {
  int t = blockIdx.x * blockDim.x + threadIdx.x;
  if (t >= NSTEPS) return;
  uint32_t o0, o1;
  tf_block(0u, 42u, 0u, (uint32_t)t, o0, o1);  // fold_in(key(42), t)
  keys[t] = make_uint2(o0, o1);
}

// ---------------- kernel 1: noise rows [r][e] (threefry_partitionable) ----
// JAX partitionable random_bits, bit_width=32: per element e,
// (b1, b2) = threefry2x32(key, (hi32(e)=0, lo32(e)=e)); draw = b1 ^ b2.
__global__ void __launch_bounds__(256) k_noise(const uint2* __restrict__ keys,
                                               float* __restrict__ buf0,
                                               int t0, int nrows) {
  const int r = blockIdx.y;
  const int e = blockIdx.x * 256 + threadIdx.x;  // [0, 16384)
  const uint2 fk = keys[t0 + r];                 // uniform -> s_load
  uint32_t o0, o1;
  tf_block(fk.x, fk.y, 0u, (uint32_t)e, o0, o1);
  buf0[(size_t)r * NE + e] = bits_to_normal(o0 ^ o1);
}

// ---------------- DPP 8-lane group reductions ----------------
template <int CTRL>
__device__ __forceinline__ float dppf(float v) {
  int r = __builtin_amdgcn_update_dpp(0, __builtin_bit_cast(int, v), CTRL, 0xF, 0xF, true);
  return __builtin_bit_cast(float, r);
}
// 0xB1 = quad_perm[1,0,3,2] (xor1), 0x4E = quad_perm[2,3,0,1] (xor2),
// 0x141 = row_half_mirror (xor within 8-lane group)

// ---------------- kernel 2: sequential recurrence ----------------
__global__ void __launch_bounds__(64) k_sim(const float* __restrict__ input,
                                            float* __restrict__ buf0,
                                            float* __restrict__ pstate,
                                            int* __restrict__ wl,
                                            int t0, int nrows, int chunk0) {
  const int lane = threadIdx.x;       // 0..63; sim = 8-lane group
  const int w = blockIdx.x;           // 0..255
  const int e = (w << 6) + lane;
  if (!chunk0 && wl[w] <= t0) return;  // frozen in an earlier chunk
  float pre = chunk0 ? 0.0f : pstate[e];
  float act = fmaxf(pre, 0.0f);
  const float inp = input[e];

  auto LD = [&](int row) -> float {
    row = (row < nrows - 1) ? row : (nrows - 1);
    return buf0[(size_t)row * NE + e];
  };
  // 3-deep, 4-wide prefetch pipeline (12 rows in flight)
  float c0 = LD(0), c1 = LD(1), c2 = LD(2), c3 = LD(3);
  float d0 = LD(4), d1 = LD(5), d2 = LD(6), d3 = LD(7);
  float f0 = LD(8), f1 = LD(9), f2 = LD(10), f3 = LD(11);

  int frozeAt = -1;
  const int ngroups = (nrows + 3) >> 2;
  for (int g = 0; g < ngroups; ++g) {
    const int base = g << 2;
    float nz[4] = {c0, c1, c2, c3};
#pragma unroll
    for (int j = 0; j < 4; ++j) {
      const int rr = base + j;
      if (rr >= nrows) break;
      // active from previous act (carry), per 8-lane sim group
      float mx = act;
      mx = fmaxf(mx, dppf<0xB1>(mx));
      mx = fmaxf(mx, dppf<0x4E>(mx));
      mx = fmaxf(mx, dppf<0x141>(mx));
      if (__ballot(mx < 1.0f) == 0ull) { frozeAt = t0 + rr; goto done; }
      const float active = (mx < 1.0f) ? 1.0f : 0.0f;
      float S = act;
      S = S + dppf<0xB1>(S);
      S = S + dppf<0x4E>(S);
      S = S + dppf<0x141>(S);
      {
#pragma clang fp contract(off)
        const float rec = (S * -0.1f) * 7.0f;   // sum(act@gamma, axis=1)
        float a = inp - 0.1f * pre;
        float b = a + rec;
        float c = b * active;
        pre = pre + c * 0.01f;
        float dwn = active * nz[j];
        pre = pre + dwn * 0.031622776601683793f;  // float(np.sqrt(0.001))
      }
      act = fmaxf(pre, 0.0f);
      buf0[(size_t)rr * NE + e] = pre;  // overwrite consumed noise row
    }
    c0 = d0; c1 = d1; c2 = d2; c3 = d3;
    d0 = f0; d1 = f1; d2 = f2; d3 = f3;
    const int pb = (g + 3) << 2;
    f0 = LD(pb); f1 = LD(pb + 1); f2 = LD(pb + 2); f3 = LD(pb + 3);
  }
done:
  pstate[e] = pre;
  if (lane == 0) {
    if (frozeAt >= 0) wl[w] = frozeAt;      // last valid tau
    else if (chunk0) wl[w] = NSTEPS;        // never frozen (so far)
  }
}

// ---------------- kernel 3: transpose/fill to [e][1501] (f32 out) --------
__global__ void __launch_bounds__(256) k_expand(const float* __restrict__ buf0,
                                                const float* __restrict__ pstate,
                                                const int* __restrict__ wl,
                                                float* __restrict__ out,
                                                int t0, int nrows, int chunk0) {
  __shared__ float lds[64 * 65];
  const int bx = blockIdx.x;         // e-tile (64 e's == one k_sim wave)
  const int by = blockIdx.y;         // tau tile
  const int tid = threadIdx.x;
  const int lane = tid & 63;
  const int wv = tid >> 6;
  const int tau_base = (chunk0 ? 0 : (t0 + 1)) + by * 64;
  const int tau_end = t0 + nrows;    // inclusive
  const int wlv = wl[bx];
  const int E0 = bx << 6;
#pragma unroll
  for (int k = 0; k < 16; ++k) {
    int tl = wv * 16 + k;
    int tau = tau_base + tl;
    float p;
    if (tau == 0) {
      p = 0.0f;
    } else if (tau <= wlv) {
      int r = tau - (t0 + 1);
      r = (r < 0) ? 0 : ((r < nrows - 1) ? r : (nrows - 1));
      p = buf0[(size_t)r * NE + E0 + lane];
    } else {
      p = pstate[E0 + lane];   // post-freeze: trajectory constant
    }
    lds[tl * 65 + lane] = p;
  }
  __syncthreads();
  const size_t actoff = (size_t)NE * TP1;
#pragma unroll
  for (int k = 0; k < 16; ++k) {
    int el = wv * 16 + k;
    int tau = tau_base + lane;
    if (tau <= tau_end) {
      float p = lds[lane * 65 + el];
      size_t o = (size_t)(E0 + el) * TP1 + tau;
      out[o] = p;
      out[actoff + o] = fmaxf(p, 0.0f);   // act == relu(pre), never stored
    }
  }
}

extern "C" void kernel_launch(void* const* d_in, const int* in_sizes, int n_in,
                              void* d_out, int out_size, void* d_ws, size_t ws_size,
                              hipStream_t stream) {
  const float* input = (const float*)d_in[0];
  float* out = (float*)d_out;
  char* ws = (char*)d_ws;
  uint2* keys = (uint2*)(ws + KEYS_OFF);
  int* wl = (int*)(ws + WL_OFF);
  float* pstate = (float*)(ws + PSTATE_OFF);
  float* buf0 = (float*)(ws + BUF0_OFF);

  size_t cap = (ws_size > BUF0_OFF) ? (ws_size - BUF0_OFF) : 0;
  size_t tc = cap / ((size_t)NE * 4);
  int Tc = (tc > NSTEPS) ? NSTEPS : (int)tc;
  if (Tc < 1) return;  // insufficient workspace

  k_fold<<<dim3((NSTEPS + 255) / 256), dim3(256), 0, stream>>>(keys);

  int nch = (NSTEPS + Tc - 1) / Tc;
  for (int c = 0; c < nch; ++c) {
    int t0 = c * Tc;
    int nrows = NSTEPS - t0;
    if (nrows > Tc) nrows = Tc;
    k_noise<<<dim3(64, nrows), dim3(256), 0, stream>>>(keys, buf0, t0, nrows);
    k_sim<<<dim3(256), dim3(64), 0, stream>>>(input, buf0, pstate, wl, t0, nrows, c == 0);
    int tau_lo = (c == 0) ? 0 : (t0 + 1);
    int tau_hi = t0 + nrows;
    int ntiles = (tau_hi - tau_lo + 1 + 63) / 64;
    k_expand<<<dim3(256, ntiles), dim3(256), 0, stream>>>(buf0, pstate, wl, out, t0, nrows, c == 0);
  }
}

// Round 7
// 306.912 us; speedup vs baseline: 1.2363x; 1.2363x over previous
//
#include <hip/hip_runtime.h>
#include <stdint.h>

#define NSIMS 2048
#define NDIM 8
#define NE (NSIMS * NDIM)      // 16384 elements per timestep
#define NSTEPS 1500
#define TP1 (NSTEPS + 1)       // 1501 trajectory columns

// ws layout (bytes)
#define KEYS_OFF 0u            // 1500 * uint2
#define WL_OFF 16384u          // 256 * int   (per-wave last valid tau)
#define PSTATE_OFF 32768u      // 16384 * float (pre state at freeze/chunk end)
#define BUF0_OFF 131072u       // Tc rows * 16384 floats (noise -> pre, in place)

// ---------------- Threefry2x32-20 (exact JAX/Random123) ----------------
__device__ __forceinline__ void tf_block(uint32_t k0, uint32_t k1,
                                         uint32_t x0, uint32_t x1,
                                         uint32_t& o0, uint32_t& o1) {
  const uint32_t k2 = k0 ^ k1 ^ 0x1BD11BDAu;
  x0 += k0; x1 += k1;
#define TF_R(r) { x0 += x1; x1 = (x1 << (r)) | (x1 >> (32 - (r))); x1 ^= x0; }
  TF_R(13) TF_R(15) TF_R(26) TF_R(6)
  x0 += k1; x1 += k2 + 1u;
  TF_R(17) TF_R(29) TF_R(16) TF_R(24)
  x0 += k2; x1 += k0 + 2u;
  TF_R(13) TF_R(15) TF_R(26) TF_R(6)
  x0 += k0; x1 += k1 + 3u;
  TF_R(17) TF_R(29) TF_R(16) TF_R(24)
  x0 += k1; x1 += k2 + 4u;
  TF_R(13) TF_R(15) TF_R(26) TF_R(6)
  x0 += k2; x1 += k0 + 5u;
#undef TF_R
  o0 = x0; o1 = x1;
}

// bits -> uniform(-0.99999994, 1) -> sqrt(2)*erfinv  (XLA constants/order)
__device__ __forceinline__ float bits_to_normal(uint32_t bits) {
#pragma clang fp contract(off)
  const float LO = -0.99999994f;  // nextafter(-1, 0); (hi - lo) == 2.0f in f32
  float f = __uint_as_float((bits >> 9) | 0x3F800000u) - 1.0f;  // [0,1)
  float u = f * 2.0f + LO;
  u = fmaxf(LO, u);
  float x2 = u * u;
  float w = -log1pf(-x2);
  float p;
  if (w < 5.0f) {
    w = w - 2.5f;
    p = 2.81022636e-08f;
    p = 3.43273939e-07f + p * w;
    p = -3.5233877e-06f + p * w;
    p = -4.39150654e-06f + p * w;
    p = 0.00021858087f + p * w;
    p = -0.00125372503f + p * w;
    p = -0.00417768164f + p * w;
    p = 0.246640727f + p * w;
    p = 1.50140941f + p * w;
  } else {
    w = sqrtf(w) - 3.0f;
    p = -0.000200214257f;
    p = 0.000100950558f + p * w;
    p = 0.00134934322f + p * w;
    p = -0.00367342844f + p * w;
    p = 0.00573950773f + p * w;
    p = -0.0076224613f + p * w;
    p = 0.00943887047f + p * w;
    p = 1.00167406f + p * w;
    p = 2.83297682f + p * w;
  }
  float ei = p * u;
  return 1.41421356f * ei;   // float32(sqrt(2)) = 0x3FB504F3
}

// ---------------- kernel 0: fold keys for all t ----------------
__global__ void k_fold(uint2* __restrict__ keys) {
  int t = blockIdx.x * blockDim.x + threadIdx.x;
  if (t >= NSTEPS) return;
  uint32_t o0, o1;
  tf_block(0u, 42u, 0u, (uint32_t)t, o0, o1);  // fold_in(key(42), t)
  keys[t] = make_uint2(o0, o1);
}

// ---------------- kernel 1: noise rows [r][e] (threefry_partitionable) ----
// JAX partitionable random_bits, bit_width=32: per element e,
// (b1, b2) = threefry2x32(key, (hi32(e)=0, lo32(e)=e)); draw = b1 ^ b2.
__global__ void __launch_bounds__(256) k_noise(const uint2* __restrict__ keys,
                                               float* __restrict__ buf0,
                                               int t0, int nrows) {
  const int r = blockIdx.y;
  const int e = blockIdx.x * 256 + threadIdx.x;  // [0, 16384)
  const uint2 fk = keys[t0 + r];                 // uniform -> s_load
  uint32_t o0, o1;
  tf_block(fk.x, fk.y, 0u, (uint32_t)e, o0, o1);
  buf0[(size_t)r * NE + e] = bits_to_normal(o0 ^ o1);
}

// ---------------- DPP 8-lane group reductions ----------------
template <int CTRL>
__device__ __forceinline__ float dppf(float v) {
  int r = __builtin_amdgcn_update_dpp(0, __builtin_bit_cast(int, v), CTRL, 0xF, 0xF, true);
  return __builtin_bit_cast(float, r);
}
// 0xB1 = quad_perm[1,0,3,2] (xor1), 0x4E = quad_perm[2,3,0,1] (xor2),
// 0x141 = row_half_mirror (xor within 8-lane group)

// ---------------- kernel 2: sequential recurrence ----------------
// 8-step groups: ballot freeze-check once/group; branchless per-step gating;
// triple-buffered 24-row noise prefetch (buffer g%3 reloaded for group g+3).
__global__ void __launch_bounds__(64) k_sim(const float* __restrict__ input,
                                            float* __restrict__ buf0,
                                            float* __restrict__ pstate,
                                            int* __restrict__ wl,
                                            int t0, int nrows, int chunk0) {
  const int lane = threadIdx.x;       // 0..63; sim = 8-lane group
  const int w = blockIdx.x;           // 0..255
  const int e = (w << 6) + lane;
  if (!chunk0 && wl[w] <= t0) return;  // frozen in an earlier chunk
  float pre = chunk0 ? 0.0f : pstate[e];
  float act = fmaxf(pre, 0.0f);
  const float inp = input[e];
  const float* srcB = buf0 + e;
  float* dst = buf0 + e;
  const int lastrow = nrows - 1;

  float mx = act;
  mx = fmaxf(mx, dppf<0xB1>(mx));
  mx = fmaxf(mx, dppf<0x4E>(mx));
  mx = fmaxf(mx, dppf<0x141>(mx));

  float nzA[8], nzB[8], nzC[8];
#define LDG8(buf, gbase)                                   \
  {                                                        \
    _Pragma("unroll")                                      \
    for (int j = 0; j < 8; ++j) {                          \
      int r = (gbase) + j;                                 \
      r = (r < lastrow) ? r : lastrow;                     \
      (buf)[j] = srcB[(size_t)r * NE];                     \
    }                                                      \
  }

  int frozeAt = -1;
  LDG8(nzA, 0) LDG8(nzB, 8) LDG8(nzC, 16)

#define GROUP8(buf, g)                                                  \
  if (frozeAt < 0) {                                                    \
    if (__ballot(mx < 1.0f) == 0ull) {                                  \
      frozeAt = t0 + ((g) << 3);                                        \
    } else {                                                            \
      _Pragma("unroll")                                                 \
      for (int j = 0; j < 8; ++j) {                                     \
        const float active = (mx < 1.0f) ? 1.0f : 0.0f;                 \
        float S = act;                                                  \
        S = S + dppf<0xB1>(S);                                          \
        S = S + dppf<0x4E>(S);                                          \
        S = S + dppf<0x141>(S);                                         \
        {                                                               \
          _Pragma("clang fp contract(off)")                             \
          const float rec = (S * -0.1f) * 7.0f;                         \
          float a = inp - 0.1f * pre;                                   \
          float b = a + rec;                                            \
          float c = b * active;                                         \
          pre = pre + c * 0.01f;                                        \
          float dwn = active * (buf)[j];                                \
          pre = pre + dwn * 0.031622776601683793f;                      \
        }                                                               \
        act = fmaxf(pre, 0.0f);                                         \
        mx = act;                                                       \
        mx = fmaxf(mx, dppf<0xB1>(mx));                                 \
        mx = fmaxf(mx, dppf<0x4E>(mx));                                 \
        mx = fmaxf(mx, dppf<0x141>(mx));                                \
        *dst = pre; dst += NE;                                          \
      }                                                                 \
      LDG8((buf), ((g) + 3) << 3)                                       \
    }                                                                   \
  }

  const int ngf = nrows >> 3;          // full 8-step groups
  const int ngf3 = ngf - (ngf % 3);
  int g = 0;
  for (; g < ngf3 && frozeAt < 0; g += 3) {
    GROUP8(nzA, g)
    GROUP8(nzB, g + 1)
    GROUP8(nzC, g + 2)
  }
  // leftover full groups: buffer identity g%3 (ngf3%3==0 -> nzA, then nzB)
  if (g < ngf) { GROUP8(nzA, g) g++; }
  if (g < ngf) { GROUP8(nzB, g) g++; }
  // tail steps (<8): direct loads, ballot each step
  for (int r = ngf << 3; r < nrows && frozeAt < 0; ++r) {
    if (__ballot(mx < 1.0f) == 0ull) { frozeAt = t0 + r; break; }
    const float nz = srcB[(size_t)r * NE];
    const float active = (mx < 1.0f) ? 1.0f : 0.0f;
    float S = act;
    S = S + dppf<0xB1>(S);
    S = S + dppf<0x4E>(S);
    S = S + dppf<0x141>(S);
    {
#pragma clang fp contract(off)
      const float rec = (S * -0.1f) * 7.0f;
      float a = inp - 0.1f * pre;
      float b = a + rec;
      float c = b * active;
      pre = pre + c * 0.01f;
      float dwn = active * nz;
      pre = pre + dwn * 0.031622776601683793f;
    }
    act = fmaxf(pre, 0.0f);
    mx = act;
    mx = fmaxf(mx, dppf<0xB1>(mx));
    mx = fmaxf(mx, dppf<0x4E>(mx));
    mx = fmaxf(mx, dppf<0x141>(mx));
    *dst = pre; dst += NE;
  }
#undef GROUP8
#undef LDG8
  pstate[e] = pre;
  if (lane == 0) {
    if (frozeAt >= 0) wl[w] = frozeAt;      // last valid tau (conservative-late ok)
    else if (chunk0) wl[w] = NSTEPS;        // never frozen (so far)
  }
}

// ---------------- kernel 3: transpose/fill to [e][1501] (f32 out) --------
__global__ void __launch_bounds__(256) k_expand(const float* __restrict__ buf0,
                                                const float* __restrict__ pstate,
                                                const int* __restrict__ wl,
                                                float* __restrict__ out,
                                                int t0, int nrows, int chunk0) {
  __shared__ float lds[64 * 65];
  const int bx = blockIdx.x;         // e-tile (64 e's == one k_sim wave)
  const int by = blockIdx.y;         // tau tile
  const int tid = threadIdx.x;
  const int lane = tid & 63;
  const int wv = tid >> 6;
  const int tau_base = (chunk0 ? 0 : (t0 + 1)) + by * 64;
  const int tau_end = t0 + nrows;    // inclusive
  const int wlv = wl[bx];
  const int E0 = bx << 6;
#pragma unroll
  for (int k = 0; k < 16; ++k) {
    int tl = wv * 16 + k;
    int tau = tau_base + tl;
    float p;
    if (tau == 0) {
      p = 0.0f;
    } else if (tau <= wlv) {
      int r = tau - (t0 + 1);
      r = (r < 0) ? 0 : ((r < nrows - 1) ? r : (nrows - 1));
      p = buf0[(size_t)r * NE + E0 + lane];
    } else {
      p = pstate[E0 + lane];   // post-freeze: trajectory constant
    }
    lds[tl * 65 + lane] = p;
  }
  __syncthreads();
  const size_t actoff = (size_t)NE * TP1;
#pragma unroll
  for (int k = 0; k < 16; ++k) {
    int el = wv * 16 + k;
    int tau = tau_base + lane;
    if (tau <= tau_end) {
      float p = lds[lane * 65 + el];
      size_t o = (size_t)(E0 + el) * TP1 + tau;
      out[o] = p;
      out[actoff + o] = fmaxf(p, 0.0f);   // act == relu(pre), never stored
    }
  }
}

extern "C" void kernel_launch(void* const* d_in, const int* in_sizes, int n_in,
                              void* d_out, int out_size, void* d_ws, size_t ws_size,
                              hipStream_t stream) {
  const float* input = (const float*)d_in[0];
  float* out = (float*)d_out;
  char* ws = (char*)d_ws;
  uint2* keys = (uint2*)(ws + KEYS_OFF);
  int* wl = (int*)(ws + WL_OFF);
  float* pstate = (float*)(ws + PSTATE_OFF);
  float* buf0 = (float*)(ws + BUF0_OFF);

  size_t cap = (ws_size > BUF0_OFF) ? (ws_size - BUF0_OFF) : 0;
  size_t tc = cap / ((size_t)NE * 4);
  int Tc = (tc > NSTEPS) ? NSTEPS : (int)tc;
  if (Tc < 1) return;  // insufficient workspace

  k_fold<<<dim3((NSTEPS + 255) / 256), dim3(256), 0, stream>>>(keys);

  int nch = (NSTEPS + Tc - 1) / Tc;
  for (int c = 0; c < nch; ++c) {
    int t0 = c * Tc;
    int nrows = NSTEPS - t0;
    if (nrows > Tc) nrows = Tc;
    k_noise<<<dim3(64, nrows), dim3(256), 0, stream>>>(keys, buf0, t0, nrows);
    k_sim<<<dim3(256), dim3(64), 0, stream>>>(input, buf0, pstate, wl, t0, nrows, c == 0);
    int tau_lo = (c == 0) ? 0 : (t0 + 1);
    int tau_hi = t0 + nrows;
    int ntiles = (tau_hi - tau_lo + 1 + 63) / 64;
    k_expand<<<dim3(256, ntiles), dim3(256), 0, stream>>>(buf0, pstate, wl, out, t0, nrows, c == 0);
  }
}

// Round 8
// 205.940 us; speedup vs baseline: 1.8425x; 1.4903x over previous
//
#include <hip/hip_runtime.h>
#include <stdint.h>

#define NSIMS 2048
#define NDIM 8
#define NE (NSIMS * NDIM)      // 16384 elements per timestep
#define NSTEPS 1500
#define TP1 (NSTEPS + 1)       // 1501 trajectory columns
#define BATCH 14               // steps per lockstep batch (7 producer waves x 2 rows)
#define NBATCH ((NSTEPS + BATCH - 1) / BATCH)   // 108 (last batch = 2 steps)
#define SENT 0x7fffffff

// ---------------- Threefry2x32-20 (exact JAX/Random123) ----------------
__device__ __forceinline__ void tf_block(uint32_t k0, uint32_t k1,
                                         uint32_t x0, uint32_t x1,
                                         uint32_t& o0, uint32_t& o1) {
  const uint32_t k2 = k0 ^ k1 ^ 0x1BD11BDAu;
  x0 += k0; x1 += k1;
#define TF_R(r) { x0 += x1; x1 = (x1 << (r)) | (x1 >> (32 - (r))); x1 ^= x0; }
  TF_R(13) TF_R(15) TF_R(26) TF_R(6)
  x0 += k1; x1 += k2 + 1u;
  TF_R(17) TF_R(29) TF_R(16) TF_R(24)
  x0 += k2; x1 += k0 + 2u;
  TF_R(13) TF_R(15) TF_R(26) TF_R(6)
  x0 += k0; x1 += k1 + 3u;
  TF_R(17) TF_R(29) TF_R(16) TF_R(24)
  x0 += k1; x1 += k2 + 4u;
  TF_R(13) TF_R(15) TF_R(26) TF_R(6)
  x0 += k2; x1 += k0 + 5u;
#undef TF_R
  o0 = x0; o1 = x1;
}

// bits -> uniform(-0.99999994, 1) -> sqrt(2)*erfinv  (XLA constants/order)
__device__ __forceinline__ float bits_to_normal(uint32_t bits) {
#pragma clang fp contract(off)
  const float LO = -0.99999994f;
  float f = __uint_as_float((bits >> 9) | 0x3F800000u) - 1.0f;  // [0,1)
  float u = f * 2.0f + LO;
  u = fmaxf(LO, u);
  float x2 = u * u;
  float w = -log1pf(-x2);
  float p;
  if (w < 5.0f) {
    w = w - 2.5f;
    p = 2.81022636e-08f;
    p = 3.43273939e-07f + p * w;
    p = -3.5233877e-06f + p * w;
    p = -4.39150654e-06f + p * w;
    p = 0.00021858087f + p * w;
    p = -0.00125372503f + p * w;
    p = -0.00417768164f + p * w;
    p = 0.246640727f + p * w;
    p = 1.50140941f + p * w;
  } else {
    w = sqrtf(w) - 3.0f;
    p = -0.000200214257f;
    p = 0.000100950558f + p * w;
    p = 0.00134934322f + p * w;
    p = -0.00367342844f + p * w;
    p = 0.00573950773f + p * w;
    p = -0.0076224613f + p * w;
    p = 0.00943887047f + p * w;
    p = 1.00167406f + p * w;
    p = 2.83297682f + p * w;
  }
  float ei = p * u;
  return 1.41421356f * ei;   // float32(sqrt(2))
}

// ---------------- kernel 0: fold keys for all t ----------------
__global__ void k_fold(uint2* __restrict__ keys) {
  int t = blockIdx.x * blockDim.x + threadIdx.x;
  if (t >= NSTEPS) return;
  uint32_t o0, o1;
  tf_block(0u, 42u, 0u, (uint32_t)t, o0, o1);  // fold_in(key(42), t)
  keys[t] = make_uint2(o0, o1);
}

// ---------------- DPP 8-lane group reductions ----------------
template <int CTRL>
__device__ __forceinline__ float dppf(float v) {
  int r = __builtin_amdgcn_update_dpp(0, __builtin_bit_cast(int, v), CTRL, 0xF, 0xF, true);
  return __builtin_bit_cast(float, r);
}
// 0xB1 = quad_perm[1,0,3,2], 0x4E = quad_perm[2,3,0,1], 0x141 = row_half_mirror

// ---------------- fused producer/consumer megakernel ----------------
// Block = 64 elements (8 sims). Wave 0: recurrence + direct [e][tau] stores.
// Waves 1..7: threefry noise for batch k+1 into LDS ring (never touches HBM).
// All sync intra-block. Uniform loop exit via LDS flag read after barrier.
__global__ void __launch_bounds__(512) k_fused(const float* __restrict__ input,
                                               const uint2* __restrict__ keys,
                                               float* __restrict__ out) {
  __shared__ float ring[2][BATCH][64];
  __shared__ float spre[64];
  __shared__ int sfz;
  const int tid = threadIdx.x;
  const int wid = tid >> 6;          // 0..7
  const int lane = tid & 63;
  const int e = ((int)blockIdx.x << 6) + lane;
  const size_t actoff = (size_t)NE * TP1;
  const size_t rowo = (size_t)e * TP1;

  if (tid == 0) sfz = SENT;

  float pre = 0.0f, act = 0.0f, mx = 0.0f, inp = 0.0f;
  if (wid == 0) {
    inp = input[e];
    out[rowo] = 0.0f;                // tau = 0 zeros
    out[actoff + rowo] = 0.0f;
  } else {
    // prologue: fill batch 0 into ring[0]; wave w owns rows w-1, w-1+7
#pragma unroll
    for (int rr = 0; rr < 2; ++rr) {
      const int j = (wid - 1) + rr * 7;
      const uint2 fk = keys[j];      // t = j (batch 0), uniform -> s_load
      uint32_t o0, o1;
      tf_block(fk.x, fk.y, 0u, (uint32_t)e, o0, o1);
      ring[0][j][lane] = bits_to_normal(o0 ^ o1);
    }
  }
  __syncthreads();

  int fillStart = SENT;
  for (int k = 0; k < NBATCH; ++k) {
    const int par = k & 1;
    const int base = k * BATCH;
    const int nst = (NSTEPS - base < BATCH) ? (NSTEPS - base) : BATCH;
    if (wid == 0) {
      float nz[BATCH];
#pragma unroll
      for (int j = 0; j < BATCH; ++j) nz[j] = ring[par][j][lane];
#pragma unroll
      for (int j = 0; j < BATCH; ++j) {
        if (j >= nst) break;         // only trips on the final batch
        const float active = (mx < 1.0f) ? 1.0f : 0.0f;
        float S = act;
        S = S + dppf<0xB1>(S);
        S = S + dppf<0x4E>(S);
        S = S + dppf<0x141>(S);
        {
#pragma clang fp contract(off)
          const float rec = (S * -0.1f) * 7.0f;   // sum(act@gamma, axis=1)
          float a = inp - 0.1f * pre;
          float b = a + rec;
          float c = b * active;
          pre = pre + c * 0.01f;
          float dwn = active * nz[j];
          pre = pre + dwn * 0.031622776601683793f; // float(np.sqrt(0.001))
        }
        act = fmaxf(pre, 0.0f);
        mx = act;
        mx = fmaxf(mx, dppf<0xB1>(mx));
        mx = fmaxf(mx, dppf<0x4E>(mx));
        mx = fmaxf(mx, dppf<0x141>(mx));
        const size_t o = rowo + (size_t)(base + j + 1);
        out[o] = pre;
        out[actoff + o] = act;
      }
      if (__ballot(mx < 1.0f) == 0ull) {   // all 8 sims frozen
        spre[lane] = pre;
        if (lane == 0) sfz = base + nst + 1;  // first tau to fill
      }
    } else {
      // produce batch k+1 into ring[par^1]
      const int nb = base + BATCH;
#pragma unroll
      for (int rr = 0; rr < 2; ++rr) {
        const int j = (wid - 1) + rr * 7;
        const int t = nb + j;
        if (t < NSTEPS) {
          const uint2 fk = keys[t];
          uint32_t o0, o1;
          tf_block(fk.x, fk.y, 0u, (uint32_t)e, o0, o1);
          ring[par ^ 1][j][lane] = bits_to_normal(o0 ^ o1);
        }
      }
    }
    __syncthreads();
    if (sfz != SENT) { fillStart = sfz; break; }   // uniform exit
  }

  if (fillStart <= NSTEPS) {
    // post-freeze: trajectory constant; all 8 waves fill the tail
    const float pf = spre[lane];
    const float af = fmaxf(pf, 0.0f);
    for (int tau = fillStart + wid; tau <= NSTEPS; tau += 8) {
      out[rowo + (size_t)tau] = pf;
      out[actoff + rowo + (size_t)tau] = af;
    }
  }
}

extern "C" void kernel_launch(void* const* d_in, const int* in_sizes, int n_in,
                              void* d_out, int out_size, void* d_ws, size_t ws_size,
                              hipStream_t stream) {
  const float* input = (const float*)d_in[0];
  float* out = (float*)d_out;
  uint2* keys = (uint2*)d_ws;   // 1500 * 8 B = 12 KB
  if (ws_size < NSTEPS * sizeof(uint2)) return;

  k_fold<<<dim3((NSTEPS + 255) / 256), dim3(256), 0, stream>>>(keys);
  k_fused<<<dim3(NSIMS / 8), dim3(512), 0, stream>>>(input, keys, out);
}

// Round 9
// 195.433 us; speedup vs baseline: 1.9416x; 1.0538x over previous
//
#include <hip/hip_runtime.h>
#include <stdint.h>

#define NSIMS 2048
#define NDIM 8
#define NE (NSIMS * NDIM)      // 16384 elements per timestep
#define NSTEPS 1500
#define TP1 (NSTEPS + 1)       // 1501 trajectory columns
#define TILE 64                // steps per lockstep tile
#define NTILE ((NSTEPS + TILE - 1) / TILE)   // 24 (last tile = 28 steps)
#define SENT 0x7fffffff

// ---------------- Threefry2x32-20 (exact JAX/Random123) ----------------
__device__ __forceinline__ void tf_block(uint32_t k0, uint32_t k1,
                                         uint32_t x0, uint32_t x1,
                                         uint32_t& o0, uint32_t& o1) {
  const uint32_t k2 = k0 ^ k1 ^ 0x1BD11BDAu;
  x0 += k0; x1 += k1;
#define TF_R(r) { x0 += x1; x1 = (x1 << (r)) | (x1 >> (32 - (r))); x1 ^= x0; }
  TF_R(13) TF_R(15) TF_R(26) TF_R(6)
  x0 += k1; x1 += k2 + 1u;
  TF_R(17) TF_R(29) TF_R(16) TF_R(24)
  x0 += k2; x1 += k0 + 2u;
  TF_R(13) TF_R(15) TF_R(26) TF_R(6)
  x0 += k0; x1 += k1 + 3u;
  TF_R(17) TF_R(29) TF_R(16) TF_R(24)
  x0 += k1; x1 += k2 + 4u;
  TF_R(13) TF_R(15) TF_R(26) TF_R(6)
  x0 += k2; x1 += k0 + 5u;
#undef TF_R
  o0 = x0; o1 = x1;
}

// bits -> uniform(-0.99999994, 1) -> sqrt(2)*erfinv  (XLA constants/order)
__device__ __forceinline__ float bits_to_normal(uint32_t bits) {
#pragma clang fp contract(off)
  const float LO = -0.99999994f;
  float f = __uint_as_float((bits >> 9) | 0x3F800000u) - 1.0f;  // [0,1)
  float u = f * 2.0f + LO;
  u = fmaxf(LO, u);
  float x2 = u * u;
  float w = -log1pf(-x2);
  float p;
  if (w < 5.0f) {
    w = w - 2.5f;
    p = 2.81022636e-08f;
    p = 3.43273939e-07f + p * w;
    p = -3.5233877e-06f + p * w;
    p = -4.39150654e-06f + p * w;
    p = 0.00021858087f + p * w;
    p = -0.00125372503f + p * w;
    p = -0.00417768164f + p * w;
    p = 0.246640727f + p * w;
    p = 1.50140941f + p * w;
  } else {
    w = sqrtf(w) - 3.0f;
    p = -0.000200214257f;
    p = 0.000100950558f + p * w;
    p = 0.00134934322f + p * w;
    p = -0.00367342844f + p * w;
    p = 0.00573950773f + p * w;
    p = -0.0076224613f + p * w;
    p = 0.00943887047f + p * w;
    p = 1.00167406f + p * w;
    p = 2.83297682f + p * w;
  }
  float ei = p * u;
  return 1.41421356f * ei;   // float32(sqrt(2))
}

// ---------------- kernel 0: fold keys for all t ----------------
__global__ void k_fold(uint2* __restrict__ keys) {
  int t = blockIdx.x * blockDim.x + threadIdx.x;
  if (t >= NSTEPS) return;
  uint32_t o0, o1;
  tf_block(0u, 42u, 0u, (uint32_t)t, o0, o1);  // fold_in(key(42), t)
  keys[t] = make_uint2(o0, o1);
}

// ---------------- DPP 8-lane group reductions ----------------
template <int CTRL>
__device__ __forceinline__ float dppf(float v) {
  int r = __builtin_amdgcn_update_dpp(0, __builtin_bit_cast(int, v), CTRL, 0xF, 0xF, true);
  return __builtin_bit_cast(float, r);
}
// 0xB1 = quad_perm[1,0,3,2], 0x4E = quad_perm[2,3,0,1], 0x141 = row_half_mirror

// ---------------- fused producer/consumer megakernel ----------------
// Block = 64 elements (8 sims), 8 waves. Wave 0: recurrence -> LDS ptile.
// Waves 1..7: threefry noise for tile k+1 into LDS ring. Every 64 steps all
// 8 waves store ptile to out with lanes over tau (fully coalesced lines).
__global__ void __launch_bounds__(512, 2) k_fused(const float* __restrict__ input,
                                                  const uint2* __restrict__ keys,
                                                  float* __restrict__ out) {
  __shared__ float ring[2][TILE][64];   // 32 KB noise double-buffer
  __shared__ float ptile[TILE][65];     // 16.6 KB pre tile (tau x e)
  __shared__ float spre[64];
  __shared__ int sfz;
  const int tid = threadIdx.x;
  const int wid = tid >> 6;          // 0..7
  const int lane = tid & 63;
  const int e0 = (int)blockIdx.x << 6;
  const int e = e0 + lane;
  const size_t actoff = (size_t)NE * TP1;

  if (tid == 0) sfz = SENT;

  float pre = 0.0f, act = 0.0f, mx = 0.0f, inp = 0.0f;
  if (wid == 0) {
    inp = input[e];
    const size_t rowo = (size_t)e * TP1;
    out[rowo] = 0.0f;                  // tau = 0 zeros
    out[actoff + rowo] = 0.0f;
  } else {
    // prologue: produce tile 0
    for (int t = wid - 1; t < TILE; t += 7) {
      const uint2 fk = keys[t];
      uint32_t o0, o1;
      tf_block(fk.x, fk.y, 0u, (uint32_t)e, o0, o1);
      ring[0][t][lane] = bits_to_normal(o0 ^ o1);
    }
  }
  __syncthreads();

  int fz = SENT;
  for (int k = 0; k < NTILE; ++k) {
    const int par = k & 1;
    const int base = k * TILE;
    const int nst = (NSTEPS - base < TILE) ? (NSTEPS - base) : TILE;
    if (wid == 0) {
      // consume 64 steps in 2 chunks of 32 (noise staged to registers)
#pragma unroll
      for (int c = 0; c < 2; ++c) {
        float nz[32];
#pragma unroll
        for (int j = 0; j < 32; ++j) nz[j] = ring[par][c * 32 + j][lane];
#pragma unroll
        for (int j = 0; j < 32; ++j) {
          const int st = c * 32 + j;
          if (st >= nst) break;        // only trips on the final tile
          const float active = (mx < 1.0f) ? 1.0f : 0.0f;
          float S = act;
          S = S + dppf<0xB1>(S);
          S = S + dppf<0x4E>(S);
          S = S + dppf<0x141>(S);
          {
#pragma clang fp contract(off)
            const float rec = (S * -0.1f) * 7.0f;   // sum(act@gamma, axis=1)
            float a = inp - 0.1f * pre;
            float b = a + rec;
            float cg = b * active;
            pre = pre + cg * 0.01f;
            float dwn = active * nz[j];
            pre = pre + dwn * 0.031622776601683793f; // float(np.sqrt(0.001))
          }
          act = fmaxf(pre, 0.0f);
          mx = act;
          mx = fmaxf(mx, dppf<0xB1>(mx));
          mx = fmaxf(mx, dppf<0x4E>(mx));
          mx = fmaxf(mx, dppf<0x141>(mx));
          ptile[st][lane] = pre;       // off the dep chain
        }
      }
      if (__ballot(mx < 1.0f) == 0ull) {   // all 8 sims frozen
        spre[lane] = pre;
        if (lane == 0) sfz = base + nst + 1;  // first tau of constant tail
      }
    } else {
      // produce tile k+1
      const int nb = base + TILE;
      for (int t = nb + wid - 1; t < nb + TILE && t < NSTEPS; t += 7) {
        const uint2 fk = keys[t];
        uint32_t o0, o1;
        tf_block(fk.x, fk.y, 0u, (uint32_t)e, o0, o1);
        ring[par ^ 1][t - nb][lane] = bits_to_normal(o0 ^ o1);
      }
    }
    __syncthreads();
    // cooperative coalesced store: wave w owns e-rows w*8..w*8+7, lanes = tau
    if (lane < nst) {
      const int tau = base + 1 + lane;
#pragma unroll
      for (int ee = 0; ee < 8; ++ee) {
        const int el = (wid << 3) + ee;
        const float p = ptile[lane][el];
        const size_t o = (size_t)(e0 + el) * TP1 + (size_t)tau;
        out[o] = p;
        out[actoff + o] = fmaxf(p, 0.0f);   // act == relu(pre)
      }
    }
    if (sfz != SENT) { fz = sfz; break; }   // uniform exit (read after barrier)
    __syncthreads();                        // protect ptile/ring reuse
  }

  if (fz <= NSTEPS) {
    // post-freeze constant tail, coalesced (lanes over tau)
#pragma unroll
    for (int ee = 0; ee < 8; ++ee) {
      const int el = (wid << 3) + ee;
      const float p = spre[el];
      const float a = fmaxf(p, 0.0f);
      const size_t ro = (size_t)(e0 + el) * TP1;
      for (int tau = fz + lane; tau <= NSTEPS; tau += 64) {
        out[ro + (size_t)tau] = p;
        out[actoff + ro + (size_t)tau] = a;
      }
    }
  }
}

extern "C" void kernel_launch(void* const* d_in, const int* in_sizes, int n_in,
                              void* d_out, int out_size, void* d_ws, size_t ws_size,
                              hipStream_t stream) {
  const float* input = (const float*)d_in[0];
  float* out = (float*)d_out;
  uint2* keys = (uint2*)d_ws;   // 1500 * 8 B = 12 KB
  if (ws_size < NSTEPS * sizeof(uint2)) return;

  k_fold<<<dim3((NSTEPS + 255) / 256), dim3(256), 0, stream>>>(keys);
  k_fused<<<dim3(NSIMS / 8), dim3(512), 0, stream>>>(input, keys, out);
}

// Round 10
// 191.408 us; speedup vs baseline: 1.9824x; 1.0210x over previous
//
#include <hip/hip_runtime.h>
#include <stdint.h>

#define NSIMS 2048
#define NDIM 8
#define NE (NSIMS * NDIM)      // 16384 elements per timestep
#define NSTEPS 1500
#define TP1 (NSTEPS + 1)       // 1501 trajectory columns
#define TILE 64                // steps per lockstep tile
#define NTILE ((NSTEPS + TILE - 1) / TILE)   // 24 (last tile = 28 steps)
#define SENT 0x7fffffff

// ---------------- Threefry2x32-20 (exact JAX/Random123) ----------------
__device__ __forceinline__ void tf_block(uint32_t k0, uint32_t k1,
                                         uint32_t x0, uint32_t x1,
                                         uint32_t& o0, uint32_t& o1) {
  const uint32_t k2 = k0 ^ k1 ^ 0x1BD11BDAu;
  x0 += k0; x1 += k1;
#define TF_R(r) { x0 += x1; x1 = (x1 << (r)) | (x1 >> (32 - (r))); x1 ^= x0; }
  TF_R(13) TF_R(15) TF_R(26) TF_R(6)
  x0 += k1; x1 += k2 + 1u;
  TF_R(17) TF_R(29) TF_R(16) TF_R(24)
  x0 += k2; x1 += k0 + 2u;
  TF_R(13) TF_R(15) TF_R(26) TF_R(6)
  x0 += k0; x1 += k1 + 3u;
  TF_R(17) TF_R(29) TF_R(16) TF_R(24)
  x0 += k1; x1 += k2 + 4u;
  TF_R(13) TF_R(15) TF_R(26) TF_R(6)
  x0 += k2; x1 += k0 + 5u;
#undef TF_R
  o0 = x0; o1 = x1;
}

// bits -> uniform(-0.99999994, 1) -> sqrt(2)*erfinv, fast path:
// w = -ln(1-u^2) via fused (1-u^2) + v_log_f32; sqrt(2) folded into coeffs.
__device__ __forceinline__ float bits_to_normal(uint32_t bits) {
#pragma clang fp contract(off)
  const float LO = -0.99999994f;
  float f = __uint_as_float((bits >> 9) | 0x3F800000u) - 1.0f;  // [0,1)
  float u = f * 2.0f + LO;
  u = fmaxf(LO, u);
  float t = __builtin_fmaf(-u, u, 1.0f);   // 1 - u^2, single rounding
  float L = __log2f(t);                    // v_log_f32
  float p;
  if (L > -7.2134752f) {                   // w < 5
    float w = __builtin_fmaf(-0.69314718f, L, -2.5f);
    p = 3.97426059e-08f;
    p = 4.85462660e-07f + p * w;
    p = -4.98282379e-06f + p * w;
    p = -6.21053119e-06f + p * w;
    p = 3.09120051e-04f + p * w;
    p = -1.77303519e-03f + p * w;
    p = -5.90813402e-03f + p * w;
    p = 3.48802730e-01f + p * w;
    p = 2.12331454e+00f + p * w;
  } else {
    float w = sqrtf(-0.69314718f * L) - 3.0f;
    p = -2.83145880e-04f;
    p = 1.42765648e-04f + p * w;
    p = 1.90826058e-03f + p * w;
    p = -5.19501312e-03f + p * w;
    p = 8.11688966e-03f + p * w;
    p = -1.07797881e-02f + p * w;
    p = 1.33485786e-02f + p * w;
    p = 1.41658104e+00f + p * w;
    p = 4.00643424e+00f + p * w;
  }
  return p * u;   // == sqrt(2)*erfinv(u) with sqrt(2) pre-folded
}

// ---------------- kernel 0: fold keys for all t ----------------
__global__ void k_fold(uint2* __restrict__ keys) {
  int t = blockIdx.x * blockDim.x + threadIdx.x;
  if (t >= NSTEPS) return;
  uint32_t o0, o1;
  tf_block(0u, 42u, 0u, (uint32_t)t, o0, o1);  // fold_in(key(42), t)
  keys[t] = make_uint2(o0, o1);
}

// ---------------- DPP 8-lane group reductions ----------------
template <int CTRL>
__device__ __forceinline__ float dppf(float v) {
  int r = __builtin_amdgcn_update_dpp(0, __builtin_bit_cast(int, v), CTRL, 0xF, 0xF, true);
  return __builtin_bit_cast(float, r);
}
// 0xB1 = quad_perm[1,0,3,2], 0x4E = quad_perm[2,3,0,1], 0x141 = row_half_mirror

// ---------------- fused producer/consumer megakernel ----------------
// Block = 64 elements (8 sims), 8 waves. Wave 0: recurrence -> LDS ptile.
// Waves 1..7: threefry noise for tile k+1 into LDS ring (keys prefetched,
// rows unrolled). Every 64 steps all 8 waves store ptile coalesced.
__global__ void __launch_bounds__(512, 2) k_fused(const float* __restrict__ input,
                                                  const uint2* __restrict__ keys,
                                                  float* __restrict__ out) {
  __shared__ float ring[2][TILE][64];   // 32 KB noise double-buffer
  __shared__ float ptile[TILE][65];     // 16.6 KB pre tile (tau x e)
  __shared__ float spre[64];
  __shared__ int sfz;
  const int tid = threadIdx.x;
  const int wid = tid >> 6;          // 0..7
  const int lane = tid & 63;
  const int e0 = (int)blockIdx.x << 6;
  const int e = e0 + lane;
  const size_t actoff = (size_t)NE * TP1;

  if (tid == 0) sfz = SENT;

  float pre = 0.0f, act = 0.0f, mx = 0.0f, inp = 0.0f;
  if (wid == 0) {
    inp = input[e];
    const size_t rowo = (size_t)e * TP1;
    out[rowo] = 0.0f;                  // tau = 0 zeros
    out[actoff + rowo] = 0.0f;
  } else {
    // prologue: produce tile 0 (rows j = wid-1 + 7*rr)
    const int j0 = wid - 1;
    uint2 fk[10];
#pragma unroll
    for (int rr = 0; rr < 10; ++rr) {
      const int j = j0 + rr * 7;
      fk[rr] = (j < TILE) ? keys[j] : make_uint2(0u, 0u);
    }
#pragma unroll
    for (int rr = 0; rr < 10; ++rr) {
      const int j = j0 + rr * 7;
      if (j < TILE) {
        uint32_t o0, o1;
        tf_block(fk[rr].x, fk[rr].y, 0u, (uint32_t)e, o0, o1);
        ring[0][j][lane] = bits_to_normal(o0 ^ o1);
      }
    }
  }
  __syncthreads();

  int fz = SENT;
  for (int k = 0; k < NTILE; ++k) {
    const int par = k & 1;
    const int base = k * TILE;
    const int nst = (NSTEPS - base < TILE) ? (NSTEPS - base) : TILE;
    if (wid == 0) {
      // consume 64 steps in 2 chunks of 32 (noise staged to registers)
#pragma unroll
      for (int c = 0; c < 2; ++c) {
        float nz[32];
#pragma unroll
        for (int j = 0; j < 32; ++j) nz[j] = ring[par][c * 32 + j][lane];
#pragma unroll
        for (int j = 0; j < 32; ++j) {
          const int st = c * 32 + j;
          if (st >= nst) break;        // only trips on the final tile
          const float active = (mx < 1.0f) ? 1.0f : 0.0f;
          float S = act;
          S = S + dppf<0xB1>(S);
          S = S + dppf<0x4E>(S);
          S = S + dppf<0x141>(S);
          {
#pragma clang fp contract(off)
            const float rec = (S * -0.1f) * 7.0f;   // sum(act@gamma, axis=1)
            float a = inp - 0.1f * pre;
            float b = a + rec;
            float cg = b * active;
            pre = pre + cg * 0.01f;
            float dwn = active * nz[j];
            pre = pre + dwn * 0.031622776601683793f; // float(np.sqrt(0.001))
          }
          act = fmaxf(pre, 0.0f);
          mx = act;
          mx = fmaxf(mx, dppf<0xB1>(mx));
          mx = fmaxf(mx, dppf<0x4E>(mx));
          mx = fmaxf(mx, dppf<0x141>(mx));
          ptile[st][lane] = pre;       // off the dep chain
        }
      }
      if (__ballot(mx < 1.0f) == 0ull) {   // all 8 sims frozen
        spre[lane] = pre;
        if (lane == 0) sfz = base + nst + 1;  // first tau of constant tail
      }
    } else {
      // produce tile k+1 (keys prefetched, rows unrolled)
      const int nb = base + TILE;
      const int j0 = wid - 1;
      uint2 fk[10];
#pragma unroll
      for (int rr = 0; rr < 10; ++rr) {
        const int j = j0 + rr * 7;
        const int t = nb + j;
        fk[rr] = (j < TILE && t < NSTEPS) ? keys[t] : make_uint2(0u, 0u);
      }
#pragma unroll
      for (int rr = 0; rr < 10; ++rr) {
        const int j = j0 + rr * 7;
        const int t = nb + j;
        if (j < TILE && t < NSTEPS) {
          uint32_t o0, o1;
          tf_block(fk[rr].x, fk[rr].y, 0u, (uint32_t)e, o0, o1);
          ring[par ^ 1][j][lane] = bits_to_normal(o0 ^ o1);
        }
      }
    }
    __syncthreads();
    // cooperative coalesced store: wave w owns e-rows w*8..w*8+7, lanes = tau
    if (lane < nst) {
      const int tau = base + 1 + lane;
#pragma unroll
      for (int ee = 0; ee < 8; ++ee) {
        const int el = (wid << 3) + ee;
        const float p = ptile[lane][el];
        const size_t o = (size_t)(e0 + el) * TP1 + (size_t)tau;
        out[o] = p;
        out[actoff + o] = fmaxf(p, 0.0f);   // act == relu(pre)
      }
    }
    if (sfz != SENT) { fz = sfz; break; }   // uniform exit (read after barrier)
    __syncthreads();                        // protect ptile/ring reuse
  }

  if (fz <= NSTEPS) {
    // post-freeze constant tail, coalesced (lanes over tau)
#pragma unroll
    for (int ee = 0; ee < 8; ++ee) {
      const int el = (wid << 3) + ee;
      const float p = spre[el];
      const float a = fmaxf(p, 0.0f);
      const size_t ro = (size_t)(e0 + el) * TP1;
      for (int tau = fz + lane; tau <= NSTEPS; tau += 64) {
        out[ro + (size_t)tau] = p;
        out[actoff + ro + (size_t)tau] = a;
      }
    }
  }
}

extern "C" void kernel_launch(void* const* d_in, const int* in_sizes, int n_in,
                              void* d_out, int out_size, void* d_ws, size_t ws_size,
                              hipStream_t stream) {
  const float* input = (const float*)d_in[0];
  float* out = (float*)d_out;
  uint2* keys = (uint2*)d_ws;   // 1500 * 8 B = 12 KB
  if (ws_size < NSTEPS * sizeof(uint2)) return;

  k_fold<<<dim3((NSTEPS + 255) / 256), dim3(256), 0, stream>>>(keys);
  k_fused<<<dim3(NSIMS / 8), dim3(512), 0, stream>>>(input, keys, out);
}

// Round 11
// 128.366 us; speedup vs baseline: 2.9560x; 1.4911x over previous
//
#include <hip/hip_runtime.h>
#include <stdint.h>

#define NSIMS 2048
#define NDIM 8
#define NE (NSIMS * NDIM)      // 16384 elements per timestep
#define NSTEPS 1500
#define TP1 (NSTEPS + 1)       // 1501 trajectory columns
#define TILE 64                // steps per lockstep tile
#define NTILE ((NSTEPS + TILE - 1) / TILE)   // 24 (last tile = 28 steps)
#define SENT 0x7fffffff

// ---------------- Threefry2x32-20 (exact JAX/Random123) ----------------
__device__ __forceinline__ void tf_block(uint32_t k0, uint32_t k1,
                                         uint32_t x0, uint32_t x1,
                                         uint32_t& o0, uint32_t& o1) {
  const uint32_t k2 = k0 ^ k1 ^ 0x1BD11BDAu;
  x0 += k0; x1 += k1;
#define TF_R(r) { x0 += x1; x1 = (x1 << (r)) | (x1 >> (32 - (r))); x1 ^= x0; }
  TF_R(13) TF_R(15) TF_R(26) TF_R(6)
  x0 += k1; x1 += k2 + 1u;
  TF_R(17) TF_R(29) TF_R(16) TF_R(24)
  x0 += k2; x1 += k0 + 2u;
  TF_R(13) TF_R(15) TF_R(26) TF_R(6)
  x0 += k0; x1 += k1 + 3u;
  TF_R(17) TF_R(29) TF_R(16) TF_R(24)
  x0 += k1; x1 += k2 + 4u;
  TF_R(13) TF_R(15) TF_R(26) TF_R(6)
  x0 += k2; x1 += k0 + 5u;
#undef TF_R
  o0 = x0; o1 = x1;
}

// bits -> uniform(-0.99999994, 1) -> sqrt(2)*erfinv, fast path (validated r10)
__device__ __forceinline__ float bits_to_normal(uint32_t bits) {
#pragma clang fp contract(off)
  const float LO = -0.99999994f;
  float f = __uint_as_float((bits >> 9) | 0x3F800000u) - 1.0f;  // [0,1)
  float u = f * 2.0f + LO;
  u = fmaxf(LO, u);
  float t = __builtin_fmaf(-u, u, 1.0f);   // 1 - u^2, single rounding
  float L = __log2f(t);                    // v_log_f32
  float p;
  if (L > -7.2134752f) {                   // w < 5
    float w = __builtin_fmaf(-0.69314718f, L, -2.5f);
    p = 3.97426059e-08f;
    p = 4.85462660e-07f + p * w;
    p = -4.98282379e-06f + p * w;
    p = -6.21053119e-06f + p * w;
    p = 3.09120051e-04f + p * w;
    p = -1.77303519e-03f + p * w;
    p = -5.90813402e-03f + p * w;
    p = 3.48802730e-01f + p * w;
    p = 2.12331454e+00f + p * w;
  } else {
    float w = sqrtf(-0.69314718f * L) - 3.0f;
    p = -2.83145880e-04f;
    p = 1.42765648e-04f + p * w;
    p = 1.90826058e-03f + p * w;
    p = -5.19501312e-03f + p * w;
    p = 8.11688966e-03f + p * w;
    p = -1.07797881e-02f + p * w;
    p = 1.33485786e-02f + p * w;
    p = 1.41658104e+00f + p * w;
    p = 4.00643424e+00f + p * w;
  }
  return p * u;   // == sqrt(2)*erfinv(u), sqrt(2) pre-folded
}

// ---------------- kernel 0: fold keys for all t ----------------
__global__ void k_fold(uint2* __restrict__ keys) {
  int t = blockIdx.x * blockDim.x + threadIdx.x;
  if (t >= NSTEPS) return;
  uint32_t o0, o1;
  tf_block(0u, 42u, 0u, (uint32_t)t, o0, o1);  // fold_in(key(42), t)
  keys[t] = make_uint2(o0, o1);
}

// ---------------- DPP 8-lane group reductions ----------------
template <int CTRL>
__device__ __forceinline__ float dppf(float v) {
  int r = __builtin_amdgcn_update_dpp(0, __builtin_bit_cast(int, v), CTRL, 0xF, 0xF, true);
  return __builtin_bit_cast(float, r);
}
template <int CTRL>
__device__ __forceinline__ int dppi(int v) {
  return __builtin_amdgcn_update_dpp(0, v, CTRL, 0xF, 0xF, true);
}
// 0xB1 = quad_perm[1,0,3,2], 0x4E = quad_perm[2,3,0,1], 0x141 = row_half_mirror

// one recurrence step; gate is a per-tile constant register (activeF),
// crossing detection is lane-local and off the carried chain.
#define STEP(ST, NZ)                                                    \
  {                                                                     \
    _Pragma("clang fp contract(off)")                                   \
    float S = act;                                                      \
    S = S + dppf<0xB1>(S);                                              \
    S = S + dppf<0x4E>(S);                                              \
    S = S + dppf<0x141>(S);                                             \
    const float rec = (S * -0.1f) * 7.0f;   /* sum(act@gamma, axis=1) */\
    float a_ = inp - 0.1f * pre;                                        \
    float b_ = a_ + rec;                                                \
    float cg = b_ * activeF;                                            \
    pre = pre + cg * 0.01f;                                             \
    float dwn = activeF * (NZ);                                         \
    pre = pre + dwn * 0.031622776601683793f; /* float(np.sqrt(0.001)) */\
    act = fmaxf(pre, 0.0f);                                             \
    fc = (act >= 1.0f) ? (((ST) < fc) ? (ST) : fc) : fc;                \
    ptile[ST][lane] = pre;                                              \
  }

// ---------------- fused producer/consumer megakernel ----------------
// Block = 64 elements (8 sims), 8 waves. Wave 0: ungated recurrence ->
// LDS ptile, tile-end crossing rollback. Waves 1..7: threefry noise for
// tile k+1 into LDS ring. Every 64 steps all 8 waves store coalesced.
__global__ void __launch_bounds__(512, 2) k_fused(const float* __restrict__ input,
                                                  const uint2* __restrict__ keys,
                                                  float* __restrict__ out) {
  __shared__ float ring[2][TILE][64];   // 32 KB noise double-buffer
  __shared__ float ptile[TILE][65];     // 16.6 KB pre tile (tau x e)
  __shared__ float spre[64];
  __shared__ int sfz;
  const int tid = threadIdx.x;
  const int wid = tid >> 6;          // 0..7
  const int lane = tid & 63;
  const int e0 = (int)blockIdx.x << 6;
  const int e = e0 + lane;
  const size_t actoff = (size_t)NE * TP1;

  if (tid == 0) sfz = SENT;

  float pre = 0.0f, act = 0.0f, activeF = 1.0f, inp = 0.0f;
  if (wid == 0) {
    inp = input[e];
    const size_t rowo = (size_t)e * TP1;
    out[rowo] = 0.0f;                  // tau = 0 zeros
    out[actoff + rowo] = 0.0f;
  } else {
    // prologue: produce tile 0 (rows j = wid-1 + 7*rr)
    const int j0 = wid - 1;
    uint2 fk[10];
#pragma unroll
    for (int rr = 0; rr < 10; ++rr) {
      const int j = j0 + rr * 7;
      fk[rr] = (j < TILE) ? keys[j] : make_uint2(0u, 0u);
    }
#pragma unroll
    for (int rr = 0; rr < 10; ++rr) {
      const int j = j0 + rr * 7;
      if (j < TILE) {
        uint32_t o0, o1;
        tf_block(fk[rr].x, fk[rr].y, 0u, (uint32_t)e, o0, o1);
        ring[0][j][lane] = bits_to_normal(o0 ^ o1);
      }
    }
  }
  __syncthreads();

  int fz = SENT;
  for (int k = 0; k < NTILE; ++k) {
    const int par = k & 1;
    const int base = k * TILE;
    const int nst = (NSTEPS - base < TILE) ? (NSTEPS - base) : TILE;
    if (wid == 0) {
      int fc = TILE;   // tile-local first-crossing step (lane-local)
      if (nst == TILE) {
        // branchless full tile: 2 chunks of 32 (noise staged to registers)
#pragma unroll
        for (int ch = 0; ch < 2; ++ch) {
          float nz[32];
#pragma unroll
          for (int j = 0; j < 32; ++j) nz[j] = ring[par][ch * 32 + j][lane];
#pragma unroll
          for (int j = 0; j < 32; ++j) STEP(ch * 32 + j, nz[j])
        }
      } else {
        // final partial tile
#pragma unroll
        for (int ch = 0; ch < 2; ++ch) {
          float nz[32];
#pragma unroll
          for (int j = 0; j < 32; ++j) nz[j] = ring[par][ch * 32 + j][lane];
#pragma unroll
          for (int j = 0; j < 32; ++j) {
            const int st = ch * 32 + j;
            if (st >= nst) break;
            STEP(st, nz[j])
          }
        }
      }
      // tile-end crossing resolution (once per tile, off hot path)
      int c = fc;
      { int t_ = dppi<0xB1>(c);  c = (t_ < c) ? t_ : c; }
      { int t_ = dppi<0x4E>(c);  c = (t_ < c) ? t_ : c; }
      { int t_ = dppi<0x141>(c); c = (t_ < c) ? t_ : c; }
      if (activeF > 0.0f && c < TILE) {
        const float fpre = ptile[c][lane];   // pre at crossing step (valid)
        for (int s = c + 1; s < TILE; ++s) ptile[s][lane] = fpre;
        pre = fpre;
        act = fmaxf(fpre, 0.0f);
        activeF = 0.0f;
      }
      if (__ballot(activeF > 0.0f) == 0ull) {   // all 8 sims frozen
        spre[lane] = pre;
        if (lane == 0) sfz = base + nst + 1;    // first tau of constant tail
      }
    } else {
      // produce tile k+1 (keys prefetched, rows unrolled)
      const int nb = base + TILE;
      const int j0 = wid - 1;
      uint2 fk[10];
#pragma unroll
      for (int rr = 0; rr < 10; ++rr) {
        const int j = j0 + rr * 7;
        const int t = nb + j;
        fk[rr] = (j < TILE && t < NSTEPS) ? keys[t] : make_uint2(0u, 0u);
      }
#pragma unroll
      for (int rr = 0; rr < 10; ++rr) {
        const int j = j0 + rr * 7;
        const int t = nb + j;
        if (j < TILE && t < NSTEPS) {
          uint32_t o0, o1;
          tf_block(fk[rr].x, fk[rr].y, 0u, (uint32_t)e, o0, o1);
          ring[par ^ 1][j][lane] = bits_to_normal(o0 ^ o1);
        }
      }
    }
    __syncthreads();
    // cooperative coalesced store: wave w owns e-rows w*8..w*8+7, lanes = tau
    if (lane < nst) {
      const int tau = base + 1 + lane;
#pragma unroll
      for (int ee = 0; ee < 8; ++ee) {
        const int el = (wid << 3) + ee;
        const float p = ptile[lane][el];
        const size_t o = (size_t)(e0 + el) * TP1 + (size_t)tau;
        out[o] = p;
        out[actoff + o] = fmaxf(p, 0.0f);   // act == relu(pre)
      }
    }
    if (sfz != SENT) { fz = sfz; break; }   // uniform exit (read after barrier)
    __syncthreads();                        // protect ptile/ring reuse
  }

  if (fz <= NSTEPS) {
    // post-freeze constant tail, coalesced (lanes over tau)
#pragma unroll
    for (int ee = 0; ee < 8; ++ee) {
      const int el = (wid << 3) + ee;
      const float p = spre[el];
      const float a = fmaxf(p, 0.0f);
      const size_t ro = (size_t)(e0 + el) * TP1;
      for (int tau = fz + lane; tau <= NSTEPS; tau += 64) {
        out[ro + (size_t)tau] = p;
        out[actoff + ro + (size_t)tau] = a;
      }
    }
  }
}

extern "C" void kernel_launch(void* const* d_in, const int* in_sizes, int n_in,
                              void* d_out, int out_size, void* d_ws, size_t ws_size,
                              hipStream_t stream) {
  const float* input = (const float*)d_in[0];
  float* out = (float*)d_out;
  uint2* keys = (uint2*)d_ws;   // 1500 * 8 B = 12 KB
  if (ws_size < NSTEPS * sizeof(uint2)) return;

  k_fold<<<dim3((NSTEPS + 255) / 256), dim3(256), 0, stream>>>(keys);
  k_fused<<<dim3(NSIMS / 8), dim3(512), 0, stream>>>(input, keys, out);
}